// Round 1
// baseline (29862.134 us; speedup 1.0000x reference)
//
#include <hip/hip_runtime.h>

// LP via PDHG, fp32 baseline.
// A: (4094, 16384) row-major fp32; b, c: (16384,) fp32. Output: scalar fp32.

constexpr int N_ROWS = 4094;       // N_NODES - 2
constexpr int M_COLS = 16384;      // M_EDGES
constexpr int M4     = M_COLS / 4; // 4096 float4 per row
constexpr int PDHG_ITERS  = 300;
constexpr int POWER_ITERS = 20;
constexpr int P_CHUNKS = 64;       // row chunks for A^T u partials
constexpr int ROWS_PER_CHUNK = 64; // 64*64 = 4096 >= 4094

// ---------------- init: x=0, y=0, v = 1/sqrt(M) ----------------
__global__ __launch_bounds__(256) void k_init(float* __restrict__ x,
                                              float* __restrict__ v,
                                              float* __restrict__ y) {
    int j = blockIdx.x * 256 + threadIdx.x;
    if (j < M_COLS) { x[j] = 0.f; v[j] = 0.0078125f; } // 1/128 exact
    if (j < N_ROWS) y[j] = 0.f;
}

// ---------------- partial[chunk][j] = sum_{i in chunk} A[i][j] * u[i] ----------------
__global__ __launch_bounds__(256) void k_at_partial(const float* __restrict__ A,
                                                    const float* __restrict__ u,
                                                    float* __restrict__ partial) {
    const int j4 = blockIdx.x * 256 + threadIdx.x;   // float4 column index
    const int r0 = blockIdx.y * ROWS_PER_CHUNK;
    const int r1 = min(r0 + ROWS_PER_CHUNK, N_ROWS);

    __shared__ float su[ROWS_PER_CHUNK];
    if (threadIdx.x < (unsigned)(r1 - r0)) su[threadIdx.x] = u[r0 + threadIdx.x];
    __syncthreads();

    const float4* __restrict__ A4 = reinterpret_cast<const float4*>(A);
    float4 acc = make_float4(0.f, 0.f, 0.f, 0.f);
    for (int i = r0; i < r1; ++i) {
        const float ui = su[i - r0];
        float4 a = A4[(size_t)i * M4 + j4];
        acc.x = fmaf(a.x, ui, acc.x);
        acc.y = fmaf(a.y, ui, acc.y);
        acc.z = fmaf(a.z, ui, acc.z);
        acc.w = fmaf(a.w, ui, acc.w);
    }
    reinterpret_cast<float4*>(partial)[(size_t)blockIdx.y * M4 + j4] = acc;
}

// ---------------- w[j] = sum_p partial[p][j] ----------------
__global__ __launch_bounds__(256) void k_reduce_w(const float* __restrict__ partial,
                                                  float* __restrict__ w) {
    int j = blockIdx.x * 256 + threadIdx.x;
    float s = 0.f;
    for (int p = 0; p < P_CHUNKS; ++p) s += partial[(size_t)p * M_COLS + j];
    w[j] = s;
}

// ---------------- PDHG x-step (fused partial-reduce):
// aty = sum_p partial[p][j]; xn = clip(x - tau*(c+aty), 0, b); z = 2xn - x; x = xn
__global__ __launch_bounds__(256) void k_x_update(const float* __restrict__ partial,
                                                  const float* __restrict__ c,
                                                  const float* __restrict__ b,
                                                  float* __restrict__ x,
                                                  float* __restrict__ z,
                                                  const float* __restrict__ scalars) {
    int j = blockIdx.x * 256 + threadIdx.x;
    const float tau = scalars[1];
    float s = 0.f;
    for (int p = 0; p < P_CHUNKS; ++p) s += partial[(size_t)p * M_COLS + j];
    float xo = x[j];
    float xn = xo - tau * (c[j] + s);
    xn = fminf(fmaxf(xn, 0.f), b[j]);
    x[j] = xn;
    z[j] = 2.f * xn - xo;
}

// ---------------- row dot: MODE 0: out[i] = A_i . vec ; MODE 1: out[i] += sigma * (A_i . vec)
template <int MODE>
__global__ __launch_bounds__(256) void k_row_dot(const float* __restrict__ A,
                                                 const float* __restrict__ vec,
                                                 float* __restrict__ out,
                                                 const float* __restrict__ scalars) {
    const int i = blockIdx.x;
    const float4* __restrict__ row = reinterpret_cast<const float4*>(A + (size_t)i * M_COLS);
    const float4* __restrict__ v4  = reinterpret_cast<const float4*>(vec);
    float s = 0.f;
    for (int k = threadIdx.x; k < M4; k += 256) {
        float4 a = row[k];
        float4 v = v4[k];
        s = fmaf(a.x, v.x, s);
        s = fmaf(a.y, v.y, s);
        s = fmaf(a.z, v.z, s);
        s = fmaf(a.w, v.w, s);
    }
    for (int o = 32; o > 0; o >>= 1) s += __shfl_down(s, o, 64);
    __shared__ float sm[4];
    if ((threadIdx.x & 63) == 0) sm[threadIdx.x >> 6] = s;
    __syncthreads();
    if (threadIdx.x == 0) {
        float t = sm[0] + sm[1] + sm[2] + sm[3];
        if (MODE == 0) out[i] = t;
        else           out[i] += scalars[1] * t;  // sigma == tau
    }
}

// ---------------- norm of w (16384): MODE 0: scalars[0]=||w|| ; MODE 1: scalars[1]=0.9/sqrt(||w||)
template <int MODE>
__global__ __launch_bounds__(1024) void k_norm(const float* __restrict__ w,
                                               float* __restrict__ scalars) {
    const float4* __restrict__ w4 = reinterpret_cast<const float4*>(w);
    float s = 0.f;
    for (int k = threadIdx.x; k < M4; k += 1024) {
        float4 a = w4[k];
        s = fmaf(a.x, a.x, s);
        s = fmaf(a.y, a.y, s);
        s = fmaf(a.z, a.z, s);
        s = fmaf(a.w, a.w, s);
    }
    for (int o = 32; o > 0; o >>= 1) s += __shfl_down(s, o, 64);
    __shared__ float sm[16];
    if ((threadIdx.x & 63) == 0) sm[threadIdx.x >> 6] = s;
    __syncthreads();
    if (threadIdx.x == 0) {
        float t = 0.f;
        for (int q = 0; q < 16; ++q) t += sm[q];
        float nrm = sqrtf(t);                 // ||w||_2
        if (MODE == 0) scalars[0] = nrm;
        else           scalars[1] = 0.9f / sqrtf(nrm); // tau = sigma = 0.9/sqrt(||A^T A v||)
    }
}

// ---------------- v = w / ||w|| ----------------
__global__ __launch_bounds__(256) void k_scale(const float* __restrict__ w,
                                               float* __restrict__ v,
                                               const float* __restrict__ scalars) {
    int j = blockIdx.x * 256 + threadIdx.x;
    v[j] = w[j] / scalars[0];
}

// ---------------- out[0] = sum_j x[j] * (-c[j]) ----------------
__global__ __launch_bounds__(1024) void k_obj(const float* __restrict__ x,
                                              const float* __restrict__ c,
                                              float* __restrict__ out) {
    float s = 0.f;
    for (int k = threadIdx.x; k < M_COLS; k += 1024) s = fmaf(x[k], -c[k], s);
    for (int o = 32; o > 0; o >>= 1) s += __shfl_down(s, o, 64);
    __shared__ float sm[16];
    if ((threadIdx.x & 63) == 0) sm[threadIdx.x >> 6] = s;
    __syncthreads();
    if (threadIdx.x == 0) {
        float t = 0.f;
        for (int q = 0; q < 16; ++q) t += sm[q];
        out[0] = t;
    }
}

extern "C" void kernel_launch(void* const* d_in, const int* in_sizes, int n_in,
                              void* d_out, int out_size, void* d_ws, size_t ws_size,
                              hipStream_t stream) {
    const float* A = (const float*)d_in[0];
    const float* b = (const float*)d_in[1];
    const float* c = (const float*)d_in[2];
    float* out = (float*)d_out;

    float* ws = (float*)d_ws;
    float* x       = ws;                       // M
    float* z       = x + M_COLS;               // M
    float* v       = z + M_COLS;               // M
    float* w       = v + M_COLS;               // M
    float* y       = w + M_COLS;               // N (padded 4096)
    float* t       = y + 4096;                 // N (padded 4096)
    float* partial = t + 4096;                 // P_CHUNKS * M
    float* scalars = partial + (size_t)P_CHUNKS * M_COLS; // [0]=||w||, [1]=tau

    dim3 b256(256);
    dim3 gM(M_COLS / 256);          // 64 blocks over columns
    dim3 gAt(M4 / 256, P_CHUNKS);   // (16, 64)
    dim3 gRow(N_ROWS);              // one block per row

    k_init<<<gM, b256, 0, stream>>>(x, v, y);

    // ---- power iteration: v <- normalize(A^T (A v)), 20 iters ----
    for (int it = 0; it < POWER_ITERS; ++it) {
        k_row_dot<0><<<gRow, b256, 0, stream>>>(A, v, t, scalars); // t = A v
        k_at_partial<<<gAt, b256, 0, stream>>>(A, t, partial);     // w = A^T t
        k_reduce_w<<<gM, b256, 0, stream>>>(partial, w);
        k_norm<0><<<1, 1024, 0, stream>>>(w, scalars);             // scalars[0] = ||w||
        k_scale<<<gM, b256, 0, stream>>>(w, v, scalars);           // v = w/||w||
    }
    // ---- nrm = sqrt(||A^T (A v)||); tau = sigma = 0.9/nrm ----
    k_row_dot<0><<<gRow, b256, 0, stream>>>(A, v, t, scalars);
    k_at_partial<<<gAt, b256, 0, stream>>>(A, t, partial);
    k_reduce_w<<<gM, b256, 0, stream>>>(partial, w);
    k_norm<1><<<1, 1024, 0, stream>>>(w, scalars);                 // scalars[1] = tau

    // ---- PDHG: 300 iters ----
    for (int it = 0; it < PDHG_ITERS; ++it) {
        k_at_partial<<<gAt, b256, 0, stream>>>(A, y, partial);                  // A^T y
        k_x_update<<<gM, b256, 0, stream>>>(partial, c, b, x, z, scalars);      // x,z
        k_row_dot<1><<<gRow, b256, 0, stream>>>(A, z, y, scalars);              // y += sigma*A z
    }

    k_obj<<<1, 1024, 0, stream>>>(x, c, out);
}

// Round 2
// 17075.354 us; speedup vs baseline: 1.7488x; 1.7488x over previous
//
#include <hip/hip_runtime.h>

// LP via PDHG. A: (4094, 16384) row-major fp32; b, c: (16384,) fp32. Out: scalar fp32.
// Round 2: A converted once to fp16 in workspace; all matvecs read fp16 A with
// fp32 accumulation -> halves the dominant memory traffic. fp32 path kept as
// fallback if ws_size is too small.

constexpr int N_ROWS = 4094;       // N_NODES - 2
constexpr int M_COLS = 16384;      // M_EDGES
constexpr int M4     = M_COLS / 4; // 4096 float4 per row
constexpr int M8     = M_COLS / 8; // 2048 half8 per row
constexpr int PDHG_ITERS  = 300;
constexpr int POWER_ITERS = 20;
constexpr int P_CHUNKS = 64;       // row chunks for A^T u partials
constexpr int ROWS_PER_CHUNK = 64; // 64*64 = 4096 >= 4094

typedef _Float16 half8 __attribute__((ext_vector_type(8)));
typedef _Float16 half_t;

// ---------------- init: x=0, y=0, v = 1/128 ----------------
__global__ __launch_bounds__(256) void k_init(float* __restrict__ x,
                                              float* __restrict__ v,
                                              float* __restrict__ y) {
    int j = blockIdx.x * 256 + threadIdx.x;
    if (j < M_COLS) { x[j] = 0.f; v[j] = 0.0078125f; }
    if (j < N_ROWS) y[j] = 0.f;
}

// ---------------- A (fp32) -> A16 (fp16), 8 elems/thread ----------------
__global__ __launch_bounds__(256) void k_convert(const float* __restrict__ A,
                                                 half_t* __restrict__ A16,
                                                 int n8) {
    int g = blockIdx.x * 256 + threadIdx.x;
    const float4* __restrict__ A4 = reinterpret_cast<const float4*>(A);
    half8* __restrict__ O8 = reinterpret_cast<half8*>(A16);
    for (; g < n8; g += gridDim.x * 256) {
        float4 a = A4[2 * g];
        float4 b = A4[2 * g + 1];
        half8 h;
        h[0] = (half_t)a.x; h[1] = (half_t)a.y; h[2] = (half_t)a.z; h[3] = (half_t)a.w;
        h[4] = (half_t)b.x; h[5] = (half_t)b.y; h[6] = (half_t)b.z; h[7] = (half_t)b.w;
        O8[g] = h;
    }
}

// ================= fp16-A kernels =================

// partial[chunk][j] = sum_{i in chunk} A16[i][j] * u[i]; 8 cols/thread
__global__ __launch_bounds__(256) void k_at_partial_h(const half_t* __restrict__ A16,
                                                      const float* __restrict__ u,
                                                      float* __restrict__ partial) {
    const int j8 = blockIdx.x * 256 + threadIdx.x;   // half8 column group
    const int r0 = blockIdx.y * ROWS_PER_CHUNK;
    const int r1 = min(r0 + ROWS_PER_CHUNK, N_ROWS);

    __shared__ float su[ROWS_PER_CHUNK];
    if (threadIdx.x < (unsigned)(r1 - r0)) su[threadIdx.x] = u[r0 + threadIdx.x];
    __syncthreads();

    const half8* __restrict__ A8 = reinterpret_cast<const half8*>(A16);
    float acc[8];
#pragma unroll
    for (int q = 0; q < 8; ++q) acc[q] = 0.f;
    for (int i = r0; i < r1; ++i) {
        const float ui = su[i - r0];
        half8 a = A8[(size_t)i * M8 + j8];
#pragma unroll
        for (int q = 0; q < 8; ++q) acc[q] = fmaf((float)a[q], ui, acc[q]);
    }
    float4* __restrict__ P4 = reinterpret_cast<float4*>(partial + (size_t)blockIdx.y * M_COLS);
    P4[2 * j8]     = make_float4(acc[0], acc[1], acc[2], acc[3]);
    P4[2 * j8 + 1] = make_float4(acc[4], acc[5], acc[6], acc[7]);
}

// row dot vs fp16 A: MODE 0: out[i] = A_i.vec ; MODE 1: out[i] += sigma*(A_i.vec)
template <int MODE>
__global__ __launch_bounds__(256) void k_row_dot_h(const half_t* __restrict__ A16,
                                                   const float* __restrict__ vec,
                                                   float* __restrict__ out,
                                                   const float* __restrict__ scalars) {
    const int i = blockIdx.x;
    const half8* __restrict__ row = reinterpret_cast<const half8*>(A16 + (size_t)i * M_COLS);
    const float4* __restrict__ v4 = reinterpret_cast<const float4*>(vec);
    float s = 0.f;
    for (int k = threadIdx.x; k < M8; k += 256) {
        half8 a = row[k];
        float4 va = v4[2 * k];
        float4 vb = v4[2 * k + 1];
        s = fmaf((float)a[0], va.x, s);
        s = fmaf((float)a[1], va.y, s);
        s = fmaf((float)a[2], va.z, s);
        s = fmaf((float)a[3], va.w, s);
        s = fmaf((float)a[4], vb.x, s);
        s = fmaf((float)a[5], vb.y, s);
        s = fmaf((float)a[6], vb.z, s);
        s = fmaf((float)a[7], vb.w, s);
    }
    for (int o = 32; o > 0; o >>= 1) s += __shfl_down(s, o, 64);
    __shared__ float sm[4];
    if ((threadIdx.x & 63) == 0) sm[threadIdx.x >> 6] = s;
    __syncthreads();
    if (threadIdx.x == 0) {
        float t = sm[0] + sm[1] + sm[2] + sm[3];
        if (MODE == 0) out[i] = t;
        else           out[i] += scalars[1] * t;  // sigma == tau
    }
}

// ================= fp32 kernels (fallback path + shared small kernels) =================

__global__ __launch_bounds__(256) void k_at_partial(const float* __restrict__ A,
                                                    const float* __restrict__ u,
                                                    float* __restrict__ partial) {
    const int j4 = blockIdx.x * 256 + threadIdx.x;
    const int r0 = blockIdx.y * ROWS_PER_CHUNK;
    const int r1 = min(r0 + ROWS_PER_CHUNK, N_ROWS);

    __shared__ float su[ROWS_PER_CHUNK];
    if (threadIdx.x < (unsigned)(r1 - r0)) su[threadIdx.x] = u[r0 + threadIdx.x];
    __syncthreads();

    const float4* __restrict__ A4 = reinterpret_cast<const float4*>(A);
    float4 acc = make_float4(0.f, 0.f, 0.f, 0.f);
    for (int i = r0; i < r1; ++i) {
        const float ui = su[i - r0];
        float4 a = A4[(size_t)i * M4 + j4];
        acc.x = fmaf(a.x, ui, acc.x);
        acc.y = fmaf(a.y, ui, acc.y);
        acc.z = fmaf(a.z, ui, acc.z);
        acc.w = fmaf(a.w, ui, acc.w);
    }
    reinterpret_cast<float4*>(partial)[(size_t)blockIdx.y * M4 + j4] = acc;
}

__global__ __launch_bounds__(256) void k_reduce_w(const float* __restrict__ partial,
                                                  float* __restrict__ w) {
    int j = blockIdx.x * 256 + threadIdx.x;
    float s = 0.f;
    for (int p = 0; p < P_CHUNKS; ++p) s += partial[(size_t)p * M_COLS + j];
    w[j] = s;
}

__global__ __launch_bounds__(256) void k_x_update(const float* __restrict__ partial,
                                                  const float* __restrict__ c,
                                                  const float* __restrict__ b,
                                                  float* __restrict__ x,
                                                  float* __restrict__ z,
                                                  const float* __restrict__ scalars) {
    int j = blockIdx.x * 256 + threadIdx.x;
    const float tau = scalars[1];
    float s = 0.f;
    for (int p = 0; p < P_CHUNKS; ++p) s += partial[(size_t)p * M_COLS + j];
    float xo = x[j];
    float xn = xo - tau * (c[j] + s);
    xn = fminf(fmaxf(xn, 0.f), b[j]);
    x[j] = xn;
    z[j] = 2.f * xn - xo;
}

template <int MODE>
__global__ __launch_bounds__(256) void k_row_dot(const float* __restrict__ A,
                                                 const float* __restrict__ vec,
                                                 float* __restrict__ out,
                                                 const float* __restrict__ scalars) {
    const int i = blockIdx.x;
    const float4* __restrict__ row = reinterpret_cast<const float4*>(A + (size_t)i * M_COLS);
    const float4* __restrict__ v4  = reinterpret_cast<const float4*>(vec);
    float s = 0.f;
    for (int k = threadIdx.x; k < M4; k += 256) {
        float4 a = row[k];
        float4 v = v4[k];
        s = fmaf(a.x, v.x, s);
        s = fmaf(a.y, v.y, s);
        s = fmaf(a.z, v.z, s);
        s = fmaf(a.w, v.w, s);
    }
    for (int o = 32; o > 0; o >>= 1) s += __shfl_down(s, o, 64);
    __shared__ float sm[4];
    if ((threadIdx.x & 63) == 0) sm[threadIdx.x >> 6] = s;
    __syncthreads();
    if (threadIdx.x == 0) {
        float t = sm[0] + sm[1] + sm[2] + sm[3];
        if (MODE == 0) out[i] = t;
        else           out[i] += scalars[1] * t;
    }
}

template <int MODE>
__global__ __launch_bounds__(1024) void k_norm(const float* __restrict__ w,
                                               float* __restrict__ scalars) {
    const float4* __restrict__ w4 = reinterpret_cast<const float4*>(w);
    float s = 0.f;
    for (int k = threadIdx.x; k < M4; k += 1024) {
        float4 a = w4[k];
        s = fmaf(a.x, a.x, s);
        s = fmaf(a.y, a.y, s);
        s = fmaf(a.z, a.z, s);
        s = fmaf(a.w, a.w, s);
    }
    for (int o = 32; o > 0; o >>= 1) s += __shfl_down(s, o, 64);
    __shared__ float sm[16];
    if ((threadIdx.x & 63) == 0) sm[threadIdx.x >> 6] = s;
    __syncthreads();
    if (threadIdx.x == 0) {
        float t = 0.f;
        for (int q = 0; q < 16; ++q) t += sm[q];
        float nrm = sqrtf(t);
        if (MODE == 0) scalars[0] = nrm;
        else           scalars[1] = 0.9f / sqrtf(nrm);
    }
}

__global__ __launch_bounds__(256) void k_scale(const float* __restrict__ w,
                                               float* __restrict__ v,
                                               const float* __restrict__ scalars) {
    int j = blockIdx.x * 256 + threadIdx.x;
    v[j] = w[j] / scalars[0];
}

__global__ __launch_bounds__(1024) void k_obj(const float* __restrict__ x,
                                              const float* __restrict__ c,
                                              float* __restrict__ out) {
    float s = 0.f;
    for (int k = threadIdx.x; k < M_COLS; k += 1024) s = fmaf(x[k], -c[k], s);
    for (int o = 32; o > 0; o >>= 1) s += __shfl_down(s, o, 64);
    __shared__ float sm[16];
    if ((threadIdx.x & 63) == 0) sm[threadIdx.x >> 6] = s;
    __syncthreads();
    if (threadIdx.x == 0) {
        float t = 0.f;
        for (int q = 0; q < 16; ++q) t += sm[q];
        out[0] = t;
    }
}

extern "C" void kernel_launch(void* const* d_in, const int* in_sizes, int n_in,
                              void* d_out, int out_size, void* d_ws, size_t ws_size,
                              hipStream_t stream) {
    const float* A = (const float*)d_in[0];
    const float* b = (const float*)d_in[1];
    const float* c = (const float*)d_in[2];
    float* out = (float*)d_out;

    float* ws = (float*)d_ws;
    float* x       = ws;                       // M
    float* z       = x + M_COLS;               // M
    float* v       = z + M_COLS;               // M
    float* w       = v + M_COLS;               // M
    float* y       = w + M_COLS;               // N (padded 4096)
    float* t       = y + 4096;                 // N (padded 4096)
    float* partial = t + 4096;                 // P_CHUNKS * M
    float* scalars = partial + (size_t)P_CHUNKS * M_COLS; // [0]=||w||, [1]=tau
    float* after   = scalars + 16;
    // align A16 to 16 bytes
    size_t off = ((size_t)after - (size_t)ws + 15) & ~(size_t)15;
    half_t* A16 = (half_t*)((char*)ws + off);
    size_t need = off + (size_t)N_ROWS * M_COLS * sizeof(half_t);

    dim3 b256(256);
    dim3 gM(M_COLS / 256);           // 64 blocks over columns
    dim3 gRow(N_ROWS);               // one block per row

    k_init<<<gM, b256, 0, stream>>>(x, v, y);

    if (ws_size >= need) {
        // ---- fp16 path ----
        const int n8 = (N_ROWS * M_COLS) / 8;
        k_convert<<<2048, b256, 0, stream>>>(A, A16, n8);

        dim3 gAt(M8 / 256, P_CHUNKS);    // (8, 64)

        for (int it = 0; it < POWER_ITERS; ++it) {
            k_row_dot_h<0><<<gRow, b256, 0, stream>>>(A16, v, t, scalars);
            k_at_partial_h<<<gAt, b256, 0, stream>>>(A16, t, partial);
            k_reduce_w<<<gM, b256, 0, stream>>>(partial, w);
            k_norm<0><<<1, 1024, 0, stream>>>(w, scalars);
            k_scale<<<gM, b256, 0, stream>>>(w, v, scalars);
        }
        k_row_dot_h<0><<<gRow, b256, 0, stream>>>(A16, v, t, scalars);
        k_at_partial_h<<<gAt, b256, 0, stream>>>(A16, t, partial);
        k_reduce_w<<<gM, b256, 0, stream>>>(partial, w);
        k_norm<1><<<1, 1024, 0, stream>>>(w, scalars);

        for (int it = 0; it < PDHG_ITERS; ++it) {
            k_at_partial_h<<<gAt, b256, 0, stream>>>(A16, y, partial);
            k_x_update<<<gM, b256, 0, stream>>>(partial, c, b, x, z, scalars);
            k_row_dot_h<1><<<gRow, b256, 0, stream>>>(A16, z, y, scalars);
        }
    } else {
        // ---- fp32 fallback (verified round-1 path) ----
        dim3 gAt(M4 / 256, P_CHUNKS);    // (16, 64)

        for (int it = 0; it < POWER_ITERS; ++it) {
            k_row_dot<0><<<gRow, b256, 0, stream>>>(A, v, t, scalars);
            k_at_partial<<<gAt, b256, 0, stream>>>(A, t, partial);
            k_reduce_w<<<gM, b256, 0, stream>>>(partial, w);
            k_norm<0><<<1, 1024, 0, stream>>>(w, scalars);
            k_scale<<<gM, b256, 0, stream>>>(w, v, scalars);
        }
        k_row_dot<0><<<gRow, b256, 0, stream>>>(A, v, t, scalars);
        k_at_partial<<<gAt, b256, 0, stream>>>(A, t, partial);
        k_reduce_w<<<gM, b256, 0, stream>>>(partial, w);
        k_norm<1><<<1, 1024, 0, stream>>>(w, scalars);

        for (int it = 0; it < PDHG_ITERS; ++it) {
            k_at_partial<<<gAt, b256, 0, stream>>>(A, y, partial);
            k_x_update<<<gM, b256, 0, stream>>>(partial, c, b, x, z, scalars);
            k_row_dot<1><<<gRow, b256, 0, stream>>>(A, z, y, scalars);
        }
    }

    k_obj<<<1, 1024, 0, stream>>>(x, c, out);
}

// Round 3
// 14296.280 us; speedup vs baseline: 2.0888x; 1.1944x over previous
//
#include <hip/hip_runtime.h>

// LP via PDHG. A: (4094, 16384) row-major fp32; b, c: (16384,) fp32. Out: scalar fp32.
// Round 3: fp16 A plus fp16 A^T (padded) copies. PDHG iteration:
//   dual path (ws >= 270 MB): k_col<1> (A^T y fused with x/z update, reads AT16)
//                              + k_row_dot_h<1> (y += sigma*A z, reads A16)   == 2 kernels, no partials
//   AT-only path (ws >= 136 MB, guaranteed): k_col<1> + k_az_partial + k_y_update<1>
// fp32 fallback kept for safety.

constexpr int N_ROWS = 4094;       // N_NODES - 2
constexpr int NPAD   = 4096;       // padded row count for AT
constexpr int M_COLS = 16384;      // M_EDGES
constexpr int M4     = M_COLS / 4;
constexpr int M8     = M_COLS / 8;
constexpr int PDHG_ITERS  = 300;
constexpr int POWER_ITERS = 20;
constexpr int P_CHUNKS = 64;
constexpr int ROWS_PER_CHUNK = 64;

typedef _Float16 half8 __attribute__((ext_vector_type(8)));
typedef _Float16 half_t;

// ---------------- init: x=0, v=1/128, y=t=0 (full 4096 incl. pads) ----------------
__global__ __launch_bounds__(256) void k_init(float* __restrict__ x,
                                              float* __restrict__ v,
                                              float* __restrict__ y,
                                              float* __restrict__ t) {
    int j = blockIdx.x * 256 + threadIdx.x;
    if (j < M_COLS) { x[j] = 0.f; v[j] = 0.0078125f; }
    if (j < NPAD) { y[j] = 0.f; t[j] = 0.f; }
}

// ---------------- A (fp32) -> A16 (fp16) ----------------
__global__ __launch_bounds__(256) void k_convert(const float* __restrict__ A,
                                                 half_t* __restrict__ A16,
                                                 int n8) {
    int g = blockIdx.x * 256 + threadIdx.x;
    const float4* __restrict__ A4 = reinterpret_cast<const float4*>(A);
    half8* __restrict__ O8 = reinterpret_cast<half8*>(A16);
    for (; g < n8; g += gridDim.x * 256) {
        float4 a = A4[2 * g];
        float4 b = A4[2 * g + 1];
        half8 h;
        h[0] = (half_t)a.x; h[1] = (half_t)a.y; h[2] = (half_t)a.z; h[3] = (half_t)a.w;
        h[4] = (half_t)b.x; h[5] = (half_t)b.y; h[6] = (half_t)b.z; h[7] = (half_t)b.w;
        O8[g] = h;
    }
}

// ---------------- A (fp32, N_ROWS x M_COLS) -> AT16 (fp16, M_COLS x NPAD, pad rows = 0) ----
__global__ __launch_bounds__(256) void k_transpose(const float* __restrict__ A,
                                                   half_t* __restrict__ AT) {
    __shared__ float tile[64][65];
    const int i0 = blockIdx.x * 64;   // source row tile
    const int j0 = blockIdx.y * 64;   // source col tile
    const int t = threadIdx.x;
    const float4* __restrict__ A4 = reinterpret_cast<const float4*>(A);
#pragma unroll
    for (int k = 0; k < 4; ++k) {
        int idx = k * 256 + t;        // 0..1023
        int r = idx >> 4, c4 = idx & 15;
        int i = i0 + r;
        float4 val = (i < N_ROWS) ? A4[((size_t)i * M_COLS + j0) / 4 + c4]
                                  : make_float4(0.f, 0.f, 0.f, 0.f);
        tile[r][c4 * 4 + 0] = val.x;
        tile[r][c4 * 4 + 1] = val.y;
        tile[r][c4 * 4 + 2] = val.z;
        tile[r][c4 * 4 + 3] = val.w;
    }
    __syncthreads();
    half8* __restrict__ O8 = reinterpret_cast<half8*>(AT);
#pragma unroll
    for (int k = 0; k < 2; ++k) {
        int idx = k * 256 + t;        // 0..511
        int j = idx >> 3, q = idx & 7;
        half8 h;
#pragma unroll
        for (int e = 0; e < 8; ++e) h[e] = (half_t)tile[q * 8 + e][j];
        O8[((size_t)(j0 + j) * NPAD + i0) / 8 + q] = h;
    }
}

// ---------------- column dot over AT rows: one wave per column j ----------------
// MODE 0: w[j] = dot(AT_j, u)
// MODE 1: g = dot(AT_j, u); xn = clip(x - tau*(c+g), 0, b); z = 2xn - x; x = xn
template <int MODE>
__global__ __launch_bounds__(256) void k_col(const half_t* __restrict__ AT,
                                             const float* __restrict__ u,
                                             const float* __restrict__ c,
                                             const float* __restrict__ b,
                                             float* __restrict__ x,
                                             float* __restrict__ z,
                                             float* __restrict__ w,
                                             const float* __restrict__ scalars) {
    const int wv   = threadIdx.x >> 6;
    const int lane = threadIdx.x & 63;
    const int j = blockIdx.x * 4 + wv;
    const half8* __restrict__ row = reinterpret_cast<const half8*>(AT + (size_t)j * NPAD);
    const float4* __restrict__ u4 = reinterpret_cast<const float4*>(u);
    float s = 0.f;
#pragma unroll
    for (int it = 0; it < NPAD / 8 / 64; ++it) {  // 8 iters
        int k = it * 64 + lane;
        half8 a = row[k];
        float4 ua = u4[2 * k];
        float4 ub = u4[2 * k + 1];
        s = fmaf((float)a[0], ua.x, s);
        s = fmaf((float)a[1], ua.y, s);
        s = fmaf((float)a[2], ua.z, s);
        s = fmaf((float)a[3], ua.w, s);
        s = fmaf((float)a[4], ub.x, s);
        s = fmaf((float)a[5], ub.y, s);
        s = fmaf((float)a[6], ub.z, s);
        s = fmaf((float)a[7], ub.w, s);
    }
#pragma unroll
    for (int o = 32; o > 0; o >>= 1) s += __shfl_down(s, o, 64);
    if (lane == 0) {
        if (MODE == 0) {
            w[j] = s;
        } else {
            float tau = scalars[1];
            float xo = x[j];
            float xn = xo - tau * (c[j] + s);
            xn = fminf(fmaxf(xn, 0.f), b[j]);
            x[j] = xn;
            z[j] = 2.f * xn - xo;
        }
    }
}

// ---------------- A z via AT (AT-only path): partial[ch][i] = sum_{j in ch} AT[j][i]*z[j] ----
__global__ __launch_bounds__(256) void k_az_partial(const half_t* __restrict__ AT,
                                                    const float* __restrict__ zv,
                                                    float* __restrict__ partial) {
    const int ch = blockIdx.y;              // 64 chunks of 256 columns
    const int j0 = ch * 256;
    const int i8 = blockIdx.x * 256 + threadIdx.x;   // half8 index over i: 0..511
    __shared__ float sz[256];
    sz[threadIdx.x] = zv[j0 + threadIdx.x];
    __syncthreads();
    const half8* __restrict__ A8 = reinterpret_cast<const half8*>(AT);
    float acc[8];
#pragma unroll
    for (int q = 0; q < 8; ++q) acc[q] = 0.f;
    for (int jj = 0; jj < 256; ++jj) {
        half8 a = A8[(size_t)(j0 + jj) * (NPAD / 8) + i8];
        float zj = sz[jj];
#pragma unroll
        for (int q = 0; q < 8; ++q) acc[q] = fmaf((float)a[q], zj, acc[q]);
    }
    float4* __restrict__ P4 = reinterpret_cast<float4*>(partial + (size_t)ch * NPAD);
    P4[2 * i8]     = make_float4(acc[0], acc[1], acc[2], acc[3]);
    P4[2 * i8 + 1] = make_float4(acc[4], acc[5], acc[6], acc[7]);
}

// ---------------- reduce partials over 64 chunks: MODE 0: out=s ; MODE 1: out += sigma*s ----
template <int MODE>
__global__ __launch_bounds__(256) void k_y_update(const float* __restrict__ partial,
                                                  float* __restrict__ out,
                                                  const float* __restrict__ scalars) {
    int i = blockIdx.x * 256 + threadIdx.x;     // 0..4095
    float s = 0.f;
    for (int p = 0; p < 64; ++p) s += partial[(size_t)p * NPAD + i];
    if (MODE == 0) out[i] = s;
    else           out[i] += scalars[1] * s;
}

// ---------------- row dot vs fp16 A (dual path): MODE 0: out=dot ; MODE 1: out += sigma*dot ----
template <int MODE>
__global__ __launch_bounds__(256) void k_row_dot_h(const half_t* __restrict__ A16,
                                                   const float* __restrict__ vec,
                                                   float* __restrict__ out,
                                                   const float* __restrict__ scalars) {
    const int i = blockIdx.x;
    const half8* __restrict__ row = reinterpret_cast<const half8*>(A16 + (size_t)i * M_COLS);
    const float4* __restrict__ v4 = reinterpret_cast<const float4*>(vec);
    float s = 0.f;
    for (int k = threadIdx.x; k < M8; k += 256) {
        half8 a = row[k];
        float4 va = v4[2 * k];
        float4 vb = v4[2 * k + 1];
        s = fmaf((float)a[0], va.x, s);
        s = fmaf((float)a[1], va.y, s);
        s = fmaf((float)a[2], va.z, s);
        s = fmaf((float)a[3], va.w, s);
        s = fmaf((float)a[4], vb.x, s);
        s = fmaf((float)a[5], vb.y, s);
        s = fmaf((float)a[6], vb.z, s);
        s = fmaf((float)a[7], vb.w, s);
    }
    for (int o = 32; o > 0; o >>= 1) s += __shfl_down(s, o, 64);
    __shared__ float sm[4];
    if ((threadIdx.x & 63) == 0) sm[threadIdx.x >> 6] = s;
    __syncthreads();
    if (threadIdx.x == 0) {
        float t = sm[0] + sm[1] + sm[2] + sm[3];
        if (MODE == 0) out[i] = t;
        else           out[i] += scalars[1] * t;
    }
}

// ================= fp32 fallback kernels =================
__global__ __launch_bounds__(256) void k_at_partial(const float* __restrict__ A,
                                                    const float* __restrict__ u,
                                                    float* __restrict__ partial) {
    const int j4 = blockIdx.x * 256 + threadIdx.x;
    const int r0 = blockIdx.y * ROWS_PER_CHUNK;
    const int r1 = min(r0 + ROWS_PER_CHUNK, N_ROWS);
    __shared__ float su[ROWS_PER_CHUNK];
    if (threadIdx.x < (unsigned)(r1 - r0)) su[threadIdx.x] = u[r0 + threadIdx.x];
    __syncthreads();
    const float4* __restrict__ A4 = reinterpret_cast<const float4*>(A);
    float4 acc = make_float4(0.f, 0.f, 0.f, 0.f);
    for (int i = r0; i < r1; ++i) {
        const float ui = su[i - r0];
        float4 a = A4[(size_t)i * M4 + j4];
        acc.x = fmaf(a.x, ui, acc.x);
        acc.y = fmaf(a.y, ui, acc.y);
        acc.z = fmaf(a.z, ui, acc.z);
        acc.w = fmaf(a.w, ui, acc.w);
    }
    reinterpret_cast<float4*>(partial)[(size_t)blockIdx.y * M4 + j4] = acc;
}

__global__ __launch_bounds__(256) void k_reduce_w(const float* __restrict__ partial,
                                                  float* __restrict__ w) {
    int j = blockIdx.x * 256 + threadIdx.x;
    float s = 0.f;
    for (int p = 0; p < P_CHUNKS; ++p) s += partial[(size_t)p * M_COLS + j];
    w[j] = s;
}

__global__ __launch_bounds__(256) void k_x_update(const float* __restrict__ partial,
                                                  const float* __restrict__ c,
                                                  const float* __restrict__ b,
                                                  float* __restrict__ x,
                                                  float* __restrict__ z,
                                                  const float* __restrict__ scalars) {
    int j = blockIdx.x * 256 + threadIdx.x;
    const float tau = scalars[1];
    float s = 0.f;
    for (int p = 0; p < P_CHUNKS; ++p) s += partial[(size_t)p * M_COLS + j];
    float xo = x[j];
    float xn = xo - tau * (c[j] + s);
    xn = fminf(fmaxf(xn, 0.f), b[j]);
    x[j] = xn;
    z[j] = 2.f * xn - xo;
}

template <int MODE>
__global__ __launch_bounds__(256) void k_row_dot(const float* __restrict__ A,
                                                 const float* __restrict__ vec,
                                                 float* __restrict__ out,
                                                 const float* __restrict__ scalars) {
    const int i = blockIdx.x;
    const float4* __restrict__ row = reinterpret_cast<const float4*>(A + (size_t)i * M_COLS);
    const float4* __restrict__ v4  = reinterpret_cast<const float4*>(vec);
    float s = 0.f;
    for (int k = threadIdx.x; k < M4; k += 256) {
        float4 a = row[k];
        float4 v = v4[k];
        s = fmaf(a.x, v.x, s);
        s = fmaf(a.y, v.y, s);
        s = fmaf(a.z, v.z, s);
        s = fmaf(a.w, v.w, s);
    }
    for (int o = 32; o > 0; o >>= 1) s += __shfl_down(s, o, 64);
    __shared__ float sm[4];
    if ((threadIdx.x & 63) == 0) sm[threadIdx.x >> 6] = s;
    __syncthreads();
    if (threadIdx.x == 0) {
        float t = sm[0] + sm[1] + sm[2] + sm[3];
        if (MODE == 0) out[i] = t;
        else           out[i] += scalars[1] * t;
    }
}

// ---------------- shared small kernels ----------------
template <int MODE>
__global__ __launch_bounds__(1024) void k_norm(const float* __restrict__ w,
                                               float* __restrict__ scalars) {
    const float4* __restrict__ w4 = reinterpret_cast<const float4*>(w);
    float s = 0.f;
    for (int k = threadIdx.x; k < M4; k += 1024) {
        float4 a = w4[k];
        s = fmaf(a.x, a.x, s);
        s = fmaf(a.y, a.y, s);
        s = fmaf(a.z, a.z, s);
        s = fmaf(a.w, a.w, s);
    }
    for (int o = 32; o > 0; o >>= 1) s += __shfl_down(s, o, 64);
    __shared__ float sm[16];
    if ((threadIdx.x & 63) == 0) sm[threadIdx.x >> 6] = s;
    __syncthreads();
    if (threadIdx.x == 0) {
        float t = 0.f;
        for (int q = 0; q < 16; ++q) t += sm[q];
        float nrm = sqrtf(t);
        if (MODE == 0) scalars[0] = nrm;
        else           scalars[1] = 0.9f / sqrtf(nrm);
    }
}

__global__ __launch_bounds__(256) void k_scale(const float* __restrict__ w,
                                               float* __restrict__ v,
                                               const float* __restrict__ scalars) {
    int j = blockIdx.x * 256 + threadIdx.x;
    v[j] = w[j] / scalars[0];
}

__global__ __launch_bounds__(1024) void k_obj(const float* __restrict__ x,
                                              const float* __restrict__ c,
                                              float* __restrict__ out) {
    float s = 0.f;
    for (int k = threadIdx.x; k < M_COLS; k += 1024) s = fmaf(x[k], -c[k], s);
    for (int o = 32; o > 0; o >>= 1) s += __shfl_down(s, o, 64);
    __shared__ float sm[16];
    if ((threadIdx.x & 63) == 0) sm[threadIdx.x >> 6] = s;
    __syncthreads();
    if (threadIdx.x == 0) {
        float t = 0.f;
        for (int q = 0; q < 16; ++q) t += sm[q];
        out[0] = t;
    }
}

extern "C" void kernel_launch(void* const* d_in, const int* in_sizes, int n_in,
                              void* d_out, int out_size, void* d_ws, size_t ws_size,
                              hipStream_t stream) {
    const float* A = (const float*)d_in[0];
    const float* b = (const float*)d_in[1];
    const float* c = (const float*)d_in[2];
    float* out = (float*)d_out;

    float* ws = (float*)d_ws;
    float* x       = ws;                        // M
    float* z       = x + M_COLS;                // M
    float* v       = z + M_COLS;                // M
    float* w       = v + M_COLS;                // M
    float* y       = w + M_COLS;                // NPAD
    float* t       = y + NPAD;                  // NPAD
    float* scalars = t + NPAD;                  // 16
    float* partial = scalars + 16;              // up to 64*M (fp32 path) / 64*NPAD (AT path)

    // fp16 buffers: AT16 right after a 1 MB partial (AT-only layout); A16 after AT16.
    size_t base = (size_t)(partial - ws) * 4;                       // bytes
    size_t at_off = (base + (size_t)64 * NPAD * 4 + 255) & ~(size_t)255;
    half_t* AT16 = (half_t*)((char*)d_ws + at_off);
    size_t at_bytes = (size_t)M_COLS * NPAD * sizeof(half_t);       // 134.2 MB
    size_t a16_off = at_off + at_bytes;
    half_t* A16 = (half_t*)((char*)d_ws + a16_off);
    size_t a16_bytes = (size_t)N_ROWS * M_COLS * sizeof(half_t);
    size_t need_dual   = a16_off + a16_bytes;                        // ~269.8 MB
    size_t need_atonly = at_off + at_bytes;                          // ~135.6 MB
    // fp32 fallback needs partial of 64*M floats
    size_t need_fp32 = base + (size_t)P_CHUNKS * M_COLS * 4;

    dim3 b256(256);
    dim3 gM(M_COLS / 256);      // 64
    dim3 gCol(M_COLS / 4);      // 4096 (4 waves/block, 1 col/wave)
    dim3 gAz(NPAD / 8 / 256, 64); // (2, 64)
    dim3 gYU(NPAD / 256);       // 16
    dim3 gRowA(N_ROWS);
    dim3 gTr(64, 256);          // transpose tiles

    k_init<<<gM, b256, 0, stream>>>(x, v, y, t);

    if (ws_size >= need_dual) {
        // ======== dual-copy path: 2 kernels per PDHG iter ========
        k_convert<<<2048, b256, 0, stream>>>(A, A16, (N_ROWS * M_COLS) / 8);
        k_transpose<<<gTr, b256, 0, stream>>>(A, AT16);

        for (int it = 0; it < POWER_ITERS; ++it) {
            k_row_dot_h<0><<<gRowA, b256, 0, stream>>>(A16, v, t, scalars);      // t = A v
            k_col<0><<<gCol, b256, 0, stream>>>(AT16, t, c, b, x, z, w, scalars); // w = A^T t
            k_norm<0><<<1, 1024, 0, stream>>>(w, scalars);
            k_scale<<<gM, b256, 0, stream>>>(w, v, scalars);
        }
        k_row_dot_h<0><<<gRowA, b256, 0, stream>>>(A16, v, t, scalars);
        k_col<0><<<gCol, b256, 0, stream>>>(AT16, t, c, b, x, z, w, scalars);
        k_norm<1><<<1, 1024, 0, stream>>>(w, scalars);                            // tau

        for (int it = 0; it < PDHG_ITERS; ++it) {
            k_col<1><<<gCol, b256, 0, stream>>>(AT16, y, c, b, x, z, w, scalars); // x,z update
            k_row_dot_h<1><<<gRowA, b256, 0, stream>>>(A16, z, y, scalars);       // y += s*Az
        }
    } else if (ws_size >= need_atonly) {
        // ======== AT-only path: 3 kernels per PDHG iter ========
        k_transpose<<<gTr, b256, 0, stream>>>(A, AT16);

        for (int it = 0; it < POWER_ITERS; ++it) {
            k_az_partial<<<gAz, b256, 0, stream>>>(AT16, v, partial);             // chunks of A v
            k_y_update<0><<<gYU, b256, 0, stream>>>(partial, t, scalars);         // t = A v
            k_col<0><<<gCol, b256, 0, stream>>>(AT16, t, c, b, x, z, w, scalars); // w = A^T t
            k_norm<0><<<1, 1024, 0, stream>>>(w, scalars);
            k_scale<<<gM, b256, 0, stream>>>(w, v, scalars);
        }
        k_az_partial<<<gAz, b256, 0, stream>>>(AT16, v, partial);
        k_y_update<0><<<gYU, b256, 0, stream>>>(partial, t, scalars);
        k_col<0><<<gCol, b256, 0, stream>>>(AT16, t, c, b, x, z, w, scalars);
        k_norm<1><<<1, 1024, 0, stream>>>(w, scalars);

        for (int it = 0; it < PDHG_ITERS; ++it) {
            k_col<1><<<gCol, b256, 0, stream>>>(AT16, y, c, b, x, z, w, scalars); // x,z update
            k_az_partial<<<gAz, b256, 0, stream>>>(AT16, z, partial);             // A z chunks
            k_y_update<1><<<gYU, b256, 0, stream>>>(partial, y, scalars);         // y += s*Az
        }
    } else if (ws_size >= need_fp32) {
        // ======== fp32 fallback (round-1 verified) ========
        dim3 gAt(M4 / 256, P_CHUNKS);
        for (int it = 0; it < POWER_ITERS; ++it) {
            k_row_dot<0><<<gRowA, b256, 0, stream>>>(A, v, t, scalars);
            k_at_partial<<<gAt, b256, 0, stream>>>(A, t, partial);
            k_reduce_w<<<gM, b256, 0, stream>>>(partial, w);
            k_norm<0><<<1, 1024, 0, stream>>>(w, scalars);
            k_scale<<<gM, b256, 0, stream>>>(w, v, scalars);
        }
        k_row_dot<0><<<gRowA, b256, 0, stream>>>(A, v, t, scalars);
        k_at_partial<<<gAt, b256, 0, stream>>>(A, t, partial);
        k_reduce_w<<<gM, b256, 0, stream>>>(partial, w);
        k_norm<1><<<1, 1024, 0, stream>>>(w, scalars);
        for (int it = 0; it < PDHG_ITERS; ++it) {
            k_at_partial<<<gAt, b256, 0, stream>>>(A, y, partial);
            k_x_update<<<gM, b256, 0, stream>>>(partial, c, b, x, z, scalars);
            k_row_dot<1><<<gRowA, b256, 0, stream>>>(A, z, y, scalars);
        }
    }

    k_obj<<<1, 1024, 0, stream>>>(x, c, out);
}